// Round 1
// baseline (311.272 us; speedup 1.0000x reference)
//
#include <hip/hip_runtime.h>
#include <stdint.h>

#define B_   8
#define N_   2048
#define F_   256
#define BN_  (B_ * N_)
#define ALPHA_ 0.2f

typedef __attribute__((ext_vector_type(8))) short  short8;
typedef __attribute__((ext_vector_type(4))) float  f32x4;

__device__ __forceinline__ unsigned short f2bf(float x) {
  uint32_t u = __float_as_uint(x);
  uint32_t r = (u + 0x7fffu + ((u >> 16) & 1u)) >> 16;  // RNE
  return (unsigned short)r;
}

// monotone float -> uint key (order-preserving), and inverse
__device__ __forceinline__ uint32_t fkey(float f) {
  uint32_t b = __float_as_uint(f);
  return b ^ (uint32_t)(((int32_t)b >> 31) | (int32_t)0x80000000);
}
__device__ __forceinline__ float ikey(uint32_t k) {
  uint32_t b = (k & 0x80000000u) ? (k ^ 0x80000000u) : ~k;
  return __uint_as_float(b);
}

__device__ __forceinline__ void nt_store4(float* p, f32x4 v) {
  __builtin_nontemporal_store(v, (f32x4*)p);
}

__device__ __forceinline__ short8 pack8(float4 a, float4 b) {
  short8 s;
  s[0] = (short)f2bf(a.x); s[1] = (short)f2bf(a.y);
  s[2] = (short)f2bf(a.z); s[3] = (short)f2bf(a.w);
  s[4] = (short)f2bf(b.x); s[5] = (short)f2bf(b.y);
  s[6] = (short)f2bf(b.z); s[7] = (short)f2bf(b.w);
  return s;
}

// ---------------- W transpose to bf16 [f][k] ----------------
__global__ void k_cvt_w(const float* __restrict__ W, unsigned short* __restrict__ WT) {
  int k = blockIdx.x, n = threadIdx.x;
  WT[n * F_ + k] = f2bf(W[k * F_ + n]);  // WT[f][k], k contiguous (MFMA B layout)
}

// ---------------- GEMM1: h = inp @ W.
// v2: 32-row tiles (512 blocks = 2/CU), A and B fragments loaded DIRECTLY from
// global (L1/L2-resident) into registers -> ZERO barriers in the k-loop.
// LDS only used in the epilogue (hT transpose + s1/s2 reduction). ----------------
__launch_bounds__(256, 2)
__global__ void k_gemm1(const float* __restrict__ inp,            // [BN][F] f32
                        const unsigned short* __restrict__ WT,    // [F][F]  bf16
                        const float* __restrict__ avec,           // [2F]
                        unsigned short* __restrict__ hT,          // [F][BN] bf16
                        float* __restrict__ s1g, float* __restrict__ s2g,
                        uint32_t* __restrict__ maxk, uint32_t* __restrict__ mink) {
  __shared__ __align__(16) unsigned short Trans[256 * 48];  // [f][i], 32 + 16 pad (16B-aligned rows)
  __shared__ float s1_lds[32], s2_lds[32];

  const int tid  = threadIdx.x;
  const int wave = tid >> 6, lane = tid & 63;
  const int n16  = lane & 15, quad = lane >> 4;
  const int i0   = blockIdx.x * 32;
  const int b    = i0 >> 11;

  if (tid < 32) { s1_lds[tid] = 0.0f; s2_lds[tid] = 0.0f; }
  __syncthreads();  // init visible before epilogue atomics (only barrier before epilogue)

  f32x4 acc[2][4];
  #pragma unroll
  for (int mt = 0; mt < 2; ++mt)
    #pragma unroll
    for (int nt = 0; nt < 4; ++nt) acc[mt][nt] = (f32x4){0.f, 0.f, 0.f, 0.f};

  // per-lane fragment base pointers (identical bytes the old LDS staging produced)
  const float* ap0 = inp + (size_t)(i0 + n16) * F_ + quad * 8;          // A rows mt=0
  const float* ap1 = ap0 + (size_t)16 * F_;                             // A rows mt=1
  const unsigned short* bp = WT + (size_t)(wave * 64 + n16) * F_ + quad * 8;

  #pragma unroll 2
  for (int k0 = 0; k0 < F_; k0 += 32) {
    float4 a00 = *(const float4*)(ap0 + k0);
    float4 a01 = *(const float4*)(ap0 + k0 + 4);
    float4 a10 = *(const float4*)(ap1 + k0);
    float4 a11 = *(const float4*)(ap1 + k0 + 4);
    short8 bf_[4];
    #pragma unroll
    for (int nt = 0; nt < 4; ++nt)
      bf_[nt] = *(const short8*)(bp + (size_t)nt * 16 * F_ + k0);
    short8 af0 = pack8(a00, a01);
    short8 af1 = pack8(a10, a11);
    #pragma unroll
    for (int nt = 0; nt < 4; ++nt) {
      acc[0][nt] = __builtin_amdgcn_mfma_f32_16x16x32_bf16(af0, bf_[nt], acc[0][nt], 0, 0, 0);
      acc[1][nt] = __builtin_amdgcn_mfma_f32_16x16x32_bf16(af1, bf_[nt], acc[1][nt], 0, 0, 0);
    }
  }

  // ---- epilogue ----
  // 1) C-tile -> LDS transpose buffer [f][i]
  #pragma unroll
  for (int mt = 0; mt < 2; ++mt)
    #pragma unroll
    for (int nt = 0; nt < 4; ++nt) {
      int f = (wave << 6) + (nt << 4) + n16;
      int i = (mt << 4) + (quad << 2);
      ushort4 pk;
      pk.x = f2bf(acc[mt][nt][0]); pk.y = f2bf(acc[mt][nt][1]);
      pk.z = f2bf(acc[mt][nt][2]); pk.w = f2bf(acc[mt][nt][3]);
      *(ushort4*)(Trans + f * 48 + i) = pk;
    }

  // 2) fused s1/s2 from f32 accumulators
  float a1v[4], a2v[4];
  #pragma unroll
  for (int nt = 0; nt < 4; ++nt) {
    int f = (wave << 6) + (nt << 4) + n16;
    a1v[nt] = avec[f];
    a2v[nt] = avec[F_ + f];
  }
  #pragma unroll
  for (int mt = 0; mt < 2; ++mt) {
    float s1p[4] = {0, 0, 0, 0}, s2p[4] = {0, 0, 0, 0};
    #pragma unroll
    for (int nt = 0; nt < 4; ++nt)
      #pragma unroll
      for (int rg = 0; rg < 4; ++rg) {
        s1p[rg] = fmaf(acc[mt][nt][rg], a1v[nt], s1p[rg]);
        s2p[rg] = fmaf(acc[mt][nt][rg], a2v[nt], s2p[rg]);
      }
    #pragma unroll
    for (int rg = 0; rg < 4; ++rg) {
      float v1 = s1p[rg], v2 = s2p[rg];
      #pragma unroll
      for (int off = 1; off < 16; off <<= 1) {
        v1 += __shfl_xor(v1, off);
        v2 += __shfl_xor(v2, off);
      }
      if (n16 == 0) {
        atomicAdd(&s1_lds[(mt << 4) + (quad << 2) + rg], v1);
        atomicAdd(&s2_lds[(mt << 4) + (quad << 2) + rg], v2);
      }
    }
  }
  __syncthreads();

  // 3) coalesced hT store: 4 lanes x 16 B = 64 B contiguous per f-row, 4 passes
  #pragma unroll
  for (int pass = 0; pass < 4; ++pass) {
    int f = pass * 64 + wave * 16 + (lane >> 2);
    int i = (lane & 3) * 8;
    short8 v = *(const short8*)(Trans + f * 48 + i);
    *(short8*)(hT + (size_t)f * BN_ + i0 + i) = v;
  }

  // 4) s1/s2 store + block min/max -> keyed global atomics
  if (tid < 32) {
    float v1 = s1_lds[tid], v2 = s2_lds[tid];
    s1g[i0 + tid] = v1;
    s2g[i0 + tid] = v2;
    float mn1 = v1, mx1 = v1, mn2 = v2, mx2 = v2;
    #pragma unroll
    for (int off = 1; off < 32; off <<= 1) {
      mn1 = fminf(mn1, __shfl_xor(mn1, off));
      mx1 = fmaxf(mx1, __shfl_xor(mx1, off));
      mn2 = fminf(mn2, __shfl_xor(mn2, off));
      mx2 = fmaxf(mx2, __shfl_xor(mx2, off));
    }
    if (tid == 0) {
      atomicMax(&maxk[b * 2 + 0], fkey(mx1));
      atomicMax(&maxk[b * 2 + 1], fkey(mx2));
      atomicMin(&mink[b * 2 + 0], fkey(mn1));
      atomicMin(&mink[b * 2 + 1], fkey(mn2));
    }
  }
}

// ---------------- GEMM2: h_prime = elu(att @ h), att on the fly.
// v2: B fragments loaded directly from L2-resident hT (no LDS staging, no
// global_load_lds). LDS only transits the 2 KB att tile (double-buffered,
// XOR-swizzled). One raw lgkm-only barrier per k-step -> att stores and hT
// loads are NEVER drained by vmcnt(0) inside the loop. ----------------
__launch_bounds__(256, 2)
__global__ void k_gemm2(const unsigned short* __restrict__ hT,  // [F][BN] bf16
                        const float* __restrict__ s1, const float* __restrict__ s2,
                        const uint32_t* __restrict__ maxk, const uint32_t* __restrict__ mink,
                        float* __restrict__ hprime,  // [B][N][F]
                        float* __restrict__ att) {   // [B][N][N]
  __shared__ __align__(16) unsigned short Atile[2][1024];  // 2 x 32x32 bf16 (2 KB each)

  const int tid  = threadIdx.x;
  const int wave = tid >> 6, lane = tid & 63;
  const int n16  = lane & 15, quad = lane >> 4;
  const int blk  = blockIdx.x;
  const int b    = blk & 7;            // batch = blk%8 -> XCD-local hT_b in L2
  const int i0   = (blk >> 3) * 32;    // 32-row tile within batch

  // normalization params (leaky_relu monotone => extremes from extremes of s1+s2)
  float mx1 = ikey(maxk[b * 2 + 0]), mx2 = ikey(maxk[b * 2 + 1]);
  float mn1 = ikey(mink[b * 2 + 0]), mn2 = ikey(mink[b * 2 + 1]);
  float smn = mn1 + mn2, smx = mx1 + mx2;
  float emn = fmaxf(smn, ALPHA_ * smn);
  float emx = fmaxf(smx, ALPHA_ * smx);
  float scale  = 30.0f / (emx - emn);
  const float uscale = -scale;                 // u = -e_norm
  const float ubias  = emn * scale + 20.0f;

  const int r_att = tid >> 3;   // 0..31
  const int c_att = tid & 7;    // j-chunk of 4
  const float s1v = s1[b * N_ + i0 + r_att];
  const float* s2b = s2 + b * N_;
  float* attrow = att + ((size_t)(b * N_ + i0 + r_att)) * N_;

  // Atile XOR swizzle (bits 4-5 ^= row&3): 8-way -> 4-way conflict on ds_read_b128,
  // preserves 8B write / 16B read contiguity.
  const int wbyte  = r_att * 64 + ((c_att * 8) ^ ((r_att & 3) << 4));
  const int rbyte0 = n16 * 64 + ((quad * 16) ^ ((n16 & 3) << 4));   // rows n16    (mt=0)
  const int rbyte1 = rbyte0 + 16 * 64;                              // rows 16+n16 (mt=1)

  // per-lane B fragment base: exactly the bytes the old LDS staging delivered
  const unsigned short* bp = hT + (size_t)(wave * 64 + n16) * BN_ + (size_t)b * N_ + quad * 8;

  f32x4 acc[2][4];
  #pragma unroll
  for (int mt = 0; mt < 2; ++mt)
    #pragma unroll
    for (int nt = 0; nt < 4; ++nt) acc[mt][nt] = (f32x4){0.f, 0.f, 0.f, 0.f};

  int buf = 0;
  for (int k0 = 0; k0 < N_; k0 += 32, buf ^= 1) {
    // issue B loads first: producer VALU + barrier wait cover the L2 latency
    short8 bf_[4];
    bf_[0] = *(const short8*)(bp + k0);
    bf_[1] = *(const short8*)(bp + (size_t)16 * BN_ + k0);
    bf_[2] = *(const short8*)(bp + (size_t)32 * BN_ + k0);
    bf_[3] = *(const short8*)(bp + (size_t)48 * BN_ + k0);

    // producer: 4 attention values/thread
    float4 va = *(const float4*)(s2b + k0 + c_att * 4);
    float v[4] = {va.x, va.y, va.z, va.w};
    #pragma unroll
    for (int jj = 0; jj < 4; ++jj) {
      float s = s1v + v[jj];
      float l = fmaxf(s, ALPHA_ * s);                       // leaky_relu
      float u = fmaf(l, uscale, ubias);                     // u = -e_norm
      float p_ = __builtin_amdgcn_rcpf(1.0f + __expf(u));   // sigmoid(e_norm)
      v[jj] = p_;
    }
    nt_store4(attrow + k0 + c_att * 4, (f32x4){v[0], v[1], v[2], v[3]});
    ushort4 spk;
    spk.x = f2bf(v[0]); spk.y = f2bf(v[1]); spk.z = f2bf(v[2]); spk.w = f2bf(v[3]);
    *(ushort4*)((char*)Atile + buf * 2048 + wbyte) = spk;

    // raw barrier: order ONLY the LDS traffic; att stores / hT loads stay in flight
    asm volatile("s_waitcnt lgkmcnt(0)" ::: "memory");  // my ds_write visible
    __builtin_amdgcn_s_barrier();                       // everyone's ds_write visible
    asm volatile("" ::: "memory");                      // pin ds_reads after barrier

    short8 af0 = *(const short8*)((const char*)Atile + buf * 2048 + rbyte0);
    short8 af1 = *(const short8*)((const char*)Atile + buf * 2048 + rbyte1);

    #pragma unroll
    for (int nt = 0; nt < 4; ++nt) {
      acc[0][nt] = __builtin_amdgcn_mfma_f32_16x16x32_bf16(af0, bf_[nt], acc[0][nt], 0, 0, 0);
      acc[1][nt] = __builtin_amdgcn_mfma_f32_16x16x32_bf16(af1, bf_[nt], acc[1][nt], 0, 0, 0);
    }
  }

  // epilogue: ELU + nontemporal store h_prime
  float* hp = hprime + ((size_t)(b * N_ + i0)) * F_;
  #pragma unroll
  for (int mt = 0; mt < 2; ++mt)
    #pragma unroll
    for (int nt = 0; nt < 4; ++nt) {
      int fcol = (wave << 6) + (nt << 4) + n16;
      int irow = (mt << 4) + (quad << 2);
      #pragma unroll
      for (int rg = 0; rg < 4; ++rg) {
        float x = acc[mt][nt][rg];
        float y = x > 0.0f ? x : (__expf(x) - 1.0f);
        __builtin_nontemporal_store(y, hp + (size_t)(irow + rg) * F_ + fcol);
      }
    }
}

// ---------------- launch ----------------
extern "C" void kernel_launch(void* const* d_in, const int* in_sizes, int n_in,
                              void* d_out, int out_size, void* d_ws, size_t ws_size,
                              hipStream_t stream) {
  const float* inp  = (const float*)d_in[0];
  // d_in[1] = adj: unused by the reference computation
  const float* W    = (const float*)d_in[2];
  const float* avec = (const float*)d_in[3];

  float* hprime = (float*)d_out;                         // [8][2048][256]
  float* att    = (float*)d_out + (size_t)B_ * N_ * F_;  // [8][2048][2048]

  char* ws = (char*)d_ws;
  unsigned short* WT = (unsigned short*)ws;                           // 128 KB
  unsigned short* hT = (unsigned short*)(ws + 131072);                // 8 MB
  float* s1          = (float*)(ws + 131072 + 8388608);               // 64 KB
  float* s2          = s1 + BN_;                                      // 64 KB
  uint32_t* maxk     = (uint32_t*)(s2 + BN_);                         // 16 u32
  uint32_t* mink     = maxk + 16;                                     // 16 u32

  (void)hipMemsetAsync(maxk, 0x00, 64, stream);   // fkey-min init for atomicMax
  (void)hipMemsetAsync(mink, 0xFF, 64, stream);   // fkey-max init for atomicMin

  k_cvt_w<<<F_, F_, 0, stream>>>(W, WT);
  k_gemm1<<<BN_ / 32, 256, 0, stream>>>(inp, WT, avec, hT, s1, s2, maxk, mink);
  k_gemm2<<<512, 256, 0, stream>>>(hT, s1, s2, maxk, mink, hprime, att);
}

// Round 2
// 269.090 us; speedup vs baseline: 1.1568x; 1.1568x over previous
//
#include <hip/hip_runtime.h>
#include <stdint.h>

#define B_   8
#define N_   2048
#define F_   256
#define BN_  (B_ * N_)
#define ALPHA_ 0.2f

typedef __attribute__((ext_vector_type(8))) short  short8;
typedef __attribute__((ext_vector_type(4))) float  f32x4;

__device__ __forceinline__ unsigned short f2bf(float x) {
  uint32_t u = __float_as_uint(x);
  uint32_t r = (u + 0x7fffu + ((u >> 16) & 1u)) >> 16;  // RNE
  return (unsigned short)r;
}

// monotone float -> uint key (order-preserving), and inverse
__device__ __forceinline__ uint32_t fkey(float f) {
  uint32_t b = __float_as_uint(f);
  return b ^ (uint32_t)(((int32_t)b >> 31) | (int32_t)0x80000000);
}
__device__ __forceinline__ float ikey(uint32_t k) {
  uint32_t b = (k & 0x80000000u) ? (k ^ 0x80000000u) : ~k;
  return __uint_as_float(b);
}

__device__ __forceinline__ void async_load16(const void* g, void* l) {
  __builtin_amdgcn_global_load_lds(
      (const __attribute__((address_space(1))) uint32_t*)g,
      (__attribute__((address_space(3))) uint32_t*)l, 16, 0, 0);
}

// nontemporal 16B store
__device__ __forceinline__ void nt_store4(float* p, f32x4 v) {
  __builtin_nontemporal_store(v, (f32x4*)p);
}

// ---------------- W transpose to bf16 [f][k] ----------------
__global__ void k_cvt_w(const float* __restrict__ W, unsigned short* __restrict__ WT) {
  int k = blockIdx.x, n = threadIdx.x;
  WT[n * F_ + k] = f2bf(W[k * F_ + n]);  // WT[f][k], k contiguous (MFMA B layout)
}

// ---------------- GEMM1 (v0, known-good): h = inp @ W, fused s1/s2 + min/max,
// writes hT bf16. Coalesced LDS staging for A (in-register cvt) and B (DMA). ----
__launch_bounds__(256, 1)
__global__ void k_gemm1(const float* __restrict__ inp,            // [BN][F] f32
                        const unsigned short* __restrict__ WT,    // [F][F]  bf16
                        const float* __restrict__ avec,           // [2F]
                        unsigned short* __restrict__ hT,          // [F][BN] bf16
                        float* __restrict__ s1g, float* __restrict__ s2g,
                        uint32_t* __restrict__ maxk, uint32_t* __restrict__ mink) {
  __shared__ __align__(16) unsigned short Atile[64 * 32];   // [r][k]
  __shared__ __align__(16) unsigned short Btile[256 * 32];  // [f][k]
  __shared__ __align__(16) unsigned short Trans[256 * 72];  // [f][i], pad 64->72
  __shared__ float s1_lds[64], s2_lds[64];

  const int tid  = threadIdx.x;
  const int wave = tid >> 6, lane = tid & 63;
  const int n16  = lane & 15, quad = lane >> 4;
  const int i0   = blockIdx.x * 64;
  const int b    = i0 >> 11;  // batch (2048 rows each; 64 | 2048)

  if (tid < 64) { s1_lds[tid] = 0.0f; s2_lds[tid] = 0.0f; }

  f32x4 acc[4][4];
  #pragma unroll
  for (int mt = 0; mt < 4; ++mt)
    #pragma unroll
    for (int nt = 0; nt < 4; ++nt) acc[mt][nt] = (f32x4){0.f, 0.f, 0.f, 0.f};

  for (int k0 = 0; k0 < F_; k0 += 32) {
    {  // stage A from f32 inp: convert in-register, ds_write_b128
      int r = tid >> 2, cp = tid & 3;
      const float* gp = inp + (size_t)(i0 + r) * F_ + k0 + cp * 8;
      float4 va = *(const float4*)gp;
      float4 vb = *(const float4*)(gp + 4);
      short8 sv;
      sv[0] = (short)f2bf(va.x); sv[1] = (short)f2bf(va.y);
      sv[2] = (short)f2bf(va.z); sv[3] = (short)f2bf(va.w);
      sv[4] = (short)f2bf(vb.x); sv[5] = (short)f2bf(vb.y);
      sv[6] = (short)f2bf(vb.z); sv[7] = (short)f2bf(vb.w);
      *(short8*)((char*)Atile + r * 64 + cp * 16) = sv;
    }
    #pragma unroll
    for (int g4 = 0; g4 < 4; ++g4) {  // stage B (bf16 WT): 4 instr/wave
      int f = (wave << 6) + (g4 << 4) + (lane >> 2);
      int p = lane & 3;
      async_load16(WT + (size_t)f * F_ + k0 + p * 8,
                   (char*)Btile + wave * 4096 + g4 * 1024);
    }
    __syncthreads();

    short8 af[4], bf_[4];
    #pragma unroll
    for (int mt = 0; mt < 4; ++mt)
      af[mt] = *(const short8*)((const char*)Atile + ((mt * 16 + n16) * 64 + quad * 16));
    #pragma unroll
    for (int nt = 0; nt < 4; ++nt)
      bf_[nt] = *(const short8*)((const char*)Btile + ((wave * 64 + nt * 16 + n16) * 64 + quad * 16));
    #pragma unroll
    for (int mt = 0; mt < 4; ++mt)
      #pragma unroll
      for (int nt = 0; nt < 4; ++nt)
        acc[mt][nt] = __builtin_amdgcn_mfma_f32_16x16x32_bf16(af[mt], bf_[nt], acc[mt][nt], 0, 0, 0);
    __syncthreads();
  }

  // ---- epilogue ----
  #pragma unroll
  for (int mt = 0; mt < 4; ++mt)
    #pragma unroll
    for (int nt = 0; nt < 4; ++nt) {
      int f = (wave << 6) + (nt << 4) + n16;
      int i = (mt << 4) + (quad << 2);
      ushort4 pk;
      pk.x = f2bf(acc[mt][nt][0]); pk.y = f2bf(acc[mt][nt][1]);
      pk.z = f2bf(acc[mt][nt][2]); pk.w = f2bf(acc[mt][nt][3]);
      *(ushort4*)(Trans + f * 72 + i) = pk;
    }

  float a1v[4], a2v[4];
  #pragma unroll
  for (int nt = 0; nt < 4; ++nt) {
    int f = (wave << 6) + (nt << 4) + n16;
    a1v[nt] = avec[f];
    a2v[nt] = avec[F_ + f];
  }
  #pragma unroll
  for (int mt = 0; mt < 4; ++mt) {
    float s1p[4] = {0, 0, 0, 0}, s2p[4] = {0, 0, 0, 0};
    #pragma unroll
    for (int nt = 0; nt < 4; ++nt)
      #pragma unroll
      for (int rg = 0; rg < 4; ++rg) {
        s1p[rg] = fmaf(acc[mt][nt][rg], a1v[nt], s1p[rg]);
        s2p[rg] = fmaf(acc[mt][nt][rg], a2v[nt], s2p[rg]);
      }
    #pragma unroll
    for (int rg = 0; rg < 4; ++rg) {
      float v1 = s1p[rg], v2 = s2p[rg];
      #pragma unroll
      for (int off = 1; off < 16; off <<= 1) {
        v1 += __shfl_xor(v1, off);
        v2 += __shfl_xor(v2, off);
      }
      if (n16 == 0) {
        atomicAdd(&s1_lds[(mt << 4) + (quad << 2) + rg], v1);
        atomicAdd(&s2_lds[(mt << 4) + (quad << 2) + rg], v2);
      }
    }
  }
  __syncthreads();

  #pragma unroll
  for (int it = 0; it < 8; ++it) {
    int f = it * 32 + wave * 8 + (lane >> 3);
    int i = (lane & 7) * 8;
    short8 v = *(const short8*)(Trans + f * 72 + i);
    *(short8*)(hT + (size_t)f * BN_ + i0 + i) = v;
  }

  if (tid < 64) {
    float v1 = s1_lds[tid], v2 = s2_lds[tid];
    s1g[i0 + tid] = v1;
    s2g[i0 + tid] = v2;
    float mn1 = v1, mx1 = v1, mn2 = v2, mx2 = v2;
    #pragma unroll
    for (int off = 1; off < 64; off <<= 1) {
      mn1 = fminf(mn1, __shfl_xor(mn1, off));
      mx1 = fmaxf(mx1, __shfl_xor(mx1, off));
      mn2 = fminf(mn2, __shfl_xor(mn2, off));
      mx2 = fmaxf(mx2, __shfl_xor(mx2, off));
    }
    if (tid == 0) {
      atomicMax(&maxk[b * 2 + 0], fkey(mx1));
      atomicMax(&maxk[b * 2 + 1], fkey(mx2));
      atomicMin(&mink[b * 2 + 0], fkey(mn1));
      atomicMin(&mink[b * 2 + 1], fkey(mn2));
    }
  }
}

// ---------------- GEMM2 v2: counted-vmcnt double-buffered pipeline.
// Coalesced global_load_lds staging for B (kept from v0); s2 in LDS so the
// producer issues NO vmem loads; ONE raw barrier/iter with
// s_waitcnt vmcnt(1) lgkmcnt(0) (vmcnt retires in issue order: the 4 stage
// DMAs for tile t, issued last iter, are the oldest; the 1 allowed
// outstanding op is this iter's att store). Stage for t+1 issues post-barrier
// and stays in flight across the next barrier. ----------------
__launch_bounds__(256, 2)
__global__ void k_gemm2(const unsigned short* __restrict__ hT,  // [F][BN] bf16
                        const float* __restrict__ s1, const float* __restrict__ s2,
                        const uint32_t* __restrict__ maxk, const uint32_t* __restrict__ mink,
                        float* __restrict__ hprime,  // [B][N][F]
                        float* __restrict__ att) {   // [B][N][N]
  __shared__ __align__(16) unsigned short Btile[2][256 * 32];  // 2 x 16 KB
  __shared__ __align__(16) unsigned short Atile[2][1024];      // 2 x 2 KB
  __shared__ __align__(16) float s2_lds[N_];                   // 8 KB

  const int tid  = threadIdx.x;
  const int wave = tid >> 6, lane = tid & 63;
  const int n16  = lane & 15, quad = lane >> 4;
  const int blk  = blockIdx.x;
  const int b    = blk & 7;            // batch = blk%8 -> XCD-local hT_b in L2
  const int i0   = (blk >> 3) * 32;    // 32-row tile within batch

  // normalization params (leaky_relu monotone => extremes from extremes of s1+s2)
  float mx1 = ikey(maxk[b * 2 + 0]), mx2 = ikey(maxk[b * 2 + 1]);
  float mn1 = ikey(mink[b * 2 + 0]), mn2 = ikey(mink[b * 2 + 1]);
  float smn = mn1 + mn2, smx = mx1 + mx2;
  float emn = fmaxf(smn, ALPHA_ * smn);
  float emx = fmaxf(smx, ALPHA_ * smx);
  float scale  = 30.0f / (emx - emn);
  const float uscale = -scale;                 // u = -e_norm
  const float ubias  = emn * scale + 20.0f;

  const int r_att = tid >> 3;   // 0..31
  const int c_att = tid & 7;    // j-chunk of 4
  const float s1v = s1[b * N_ + i0 + r_att];
  const float* s2b = s2 + b * N_;
  float* attrow = att + ((size_t)(b * N_ + i0 + r_att)) * N_;

  auto stage_b = [&](int buf_, int k0_) {
    #pragma unroll
    for (int g4 = 0; g4 < 4; ++g4) {  // 4 instr/wave, 64B-contiguous segments
      int f = (wave << 6) + (g4 << 4) + (lane >> 2);
      int p = lane & 3;
      async_load16(hT + (size_t)f * BN_ + b * N_ + k0_ + p * 8,
                   (char*)Btile + buf_ * 16384 + wave * 4096 + g4 * 1024);
    }
  };

  // ---- prologue: stage s2 row (8 KB) + Btile[0]; one full drain (once) ----
  #pragma unroll
  for (int it = 0; it < 2; ++it)
    async_load16(s2b + wave * 512 + it * 256 + lane * 4,
                 (char*)s2_lds + wave * 2048 + it * 1024);
  stage_b(0, 0);
  asm volatile("s_waitcnt vmcnt(0) lgkmcnt(0)" ::: "memory");
  __builtin_amdgcn_s_barrier();
  asm volatile("" ::: "memory");

  f32x4 acc[2][4];
  #pragma unroll
  for (int mt = 0; mt < 2; ++mt)
    #pragma unroll
    for (int nt = 0; nt < 4; ++nt) acc[mt][nt] = (f32x4){0.f, 0.f, 0.f, 0.f};

  for (int t = 0; t < 64; ++t) {
    const int cur = t & 1;
    const int k0  = t << 5;

    // producer: 4 attention values/thread; s2 from LDS (no vmem load here)
    float4 va = *(const float4*)((const char*)s2_lds + k0 * 4 + c_att * 16);
    float v[4] = {va.x, va.y, va.z, va.w};
    #pragma unroll
    for (int jj = 0; jj < 4; ++jj) {
      float s = s1v + v[jj];
      float l = fmaxf(s, ALPHA_ * s);                       // leaky_relu
      float u = fmaf(l, uscale, ubias);                     // u = -e_norm
      float p_ = __builtin_amdgcn_rcpf(1.0f + __expf(u));   // sigmoid(e_norm)
      v[jj] = p_;
    }
    nt_store4(attrow + k0 + c_att * 4, (f32x4){v[0], v[1], v[2], v[3]});
    ushort4 spk;
    spk.x = f2bf(v[0]); spk.y = f2bf(v[1]); spk.z = f2bf(v[2]); spk.w = f2bf(v[3]);
    *(ushort4*)((char*)Atile + cur * 2048 + tid * 8) = spk;  // [r_att][c_att*4]

    // counted wait: tile-t stages (oldest 4+1) done; this iter's att store may
    // remain in flight. lgkmcnt(0): my Atile ds_write visible before barrier.
    asm volatile("s_waitcnt vmcnt(1) lgkmcnt(0)" ::: "memory");
    __builtin_amdgcn_s_barrier();
    asm volatile("" ::: "memory");

    short8 af0 = *(const short8*)((const char*)Atile + cur * 2048 + n16 * 64 + quad * 16);
    short8 af1 = *(const short8*)((const char*)Atile + cur * 2048 + (16 + n16) * 64 + quad * 16);
    short8 bf_[4];
    #pragma unroll
    for (int nt = 0; nt < 4; ++nt)
      bf_[nt] = *(const short8*)((const char*)Btile + cur * 16384 +
                                 (wave * 64 + nt * 16 + n16) * 64 + quad * 16);

    // prefetch tile t+1 into the other buffer; stays in flight across the
    // next barrier (no drain until its own vmcnt(1) next iteration).
    if (t < 63) stage_b(cur ^ 1, k0 + 32);

    #pragma unroll
    for (int nt = 0; nt < 4; ++nt) {
      acc[0][nt] = __builtin_amdgcn_mfma_f32_16x16x32_bf16(af0, bf_[nt], acc[0][nt], 0, 0, 0);
      acc[1][nt] = __builtin_amdgcn_mfma_f32_16x16x32_bf16(af1, bf_[nt], acc[1][nt], 0, 0, 0);
    }
  }

  // epilogue: ELU + nontemporal store h_prime
  float* hp = hprime + ((size_t)(b * N_ + i0)) * F_;
  #pragma unroll
  for (int mt = 0; mt < 2; ++mt)
    #pragma unroll
    for (int nt = 0; nt < 4; ++nt) {
      int fcol = (wave << 6) + (nt << 4) + n16;
      int irow = (mt << 4) + (quad << 2);
      #pragma unroll
      for (int rg = 0; rg < 4; ++rg) {
        float x = acc[mt][nt][rg];
        float y = x > 0.0f ? x : (__expf(x) - 1.0f);
        __builtin_nontemporal_store(y, hp + (size_t)(irow + rg) * F_ + fcol);
      }
    }
}

// ---------------- launch ----------------
extern "C" void kernel_launch(void* const* d_in, const int* in_sizes, int n_in,
                              void* d_out, int out_size, void* d_ws, size_t ws_size,
                              hipStream_t stream) {
  const float* inp  = (const float*)d_in[0];
  // d_in[1] = adj: unused by the reference computation
  const float* W    = (const float*)d_in[2];
  const float* avec = (const float*)d_in[3];

  float* hprime = (float*)d_out;                         // [8][2048][256]
  float* att    = (float*)d_out + (size_t)B_ * N_ * F_;  // [8][2048][2048]

  char* ws = (char*)d_ws;
  unsigned short* WT = (unsigned short*)ws;                           // 128 KB
  unsigned short* hT = (unsigned short*)(ws + 131072);                // 8 MB
  float* s1          = (float*)(ws + 131072 + 8388608);               // 64 KB
  float* s2          = s1 + BN_;                                      // 64 KB
  uint32_t* maxk     = (uint32_t*)(s2 + BN_);                         // 16 u32
  uint32_t* mink     = maxk + 16;                                     // 16 u32

  (void)hipMemsetAsync(maxk, 0x00, 64, stream);   // fkey-min init for atomicMax
  (void)hipMemsetAsync(mink, 0xFF, 64, stream);   // fkey-max init for atomicMin

  k_cvt_w<<<F_, F_, 0, stream>>>(W, WT);
  k_gemm1<<<BN_ / 64, 256, 0, stream>>>(inp, WT, avec, hT, s1, s2, maxk, mink);
  k_gemm2<<<512, 256, 0, stream>>>(hT, s1, s2, maxk, mink, hprime, att);
}